// Round 6
// baseline (494.451 us; speedup 1.0000x reference)
//
#include <hip/hip_runtime.h>
#include <hip/hip_bf16.h>
#include <math.h>

// Swin Transformer 3D block, MI355X (gfx950).  R6.
// prep_kernel: weights re-laid-out FRAGMENT-LINEAR in d_ws (each MFMA
//   operand fragment = contiguous 1KB, lane*8 order; Q-scale folded) +
//   rel-pos bias in swapped score C-fragment layout.
// attn_kernel: as R5 (passed), but weight fragments load as contiguous 1KB.
// mlp_kernel: GEMM1 swapped (C'[hid][tok]) -> GELU in-reg -> shfl transform
//   (same verified algebra as attn P->PV) -> GEMM2. No HS, no weight LDS:
//   LDS = XS only (26.6KB), 1 barrier/block.

#define NTOK 98
#define SCALE 0.17677669529663687f

// fragment ids (x512 elems): qkv 0..53, proj 54..71, fc1 72..143, fc2 144..215
#define FR_PROJ 54
#define FR_FC1  72
#define FR_FC2  144
#define WS_BF16_N 110592
#define WS_BIASM_BYTE 221184
#define WS_NEED   371712

typedef __attribute__((ext_vector_type(8))) short bf16x8;
typedef __attribute__((ext_vector_type(4))) float f32x4;

__device__ __forceinline__ int row_of(int wid, int t) {
    int b = wid >> 8, rem = wid & 255;
    int d0 = rem >> 6, h0 = (rem >> 3) & 7, w0 = rem & 7;
    int td = t / 49, tr = t % 49, th = tr / 7, tw = tr % 7;
    int dd = d0 * 2 + td, hh = h0 * 7 + th, ww = w0 * 7 + tw;
    return ((b * 8 + dd) * 56 + hh) * 56 + ww;
}

__device__ __forceinline__ int pcode(int t) {
    int a = t / 49, r = t - 49 * a, b = r / 7, c = r - 7 * b;
    return a * 169 + b * 13 + c;
}

__device__ __forceinline__ unsigned short f2bfu(float f) {
    __hip_bfloat16 h = __float2bfloat16(f);
    unsigned short u; __builtin_memcpy(&u, &h, 2); return u;
}
__device__ __forceinline__ unsigned int pk2(float lo, float hi) {
    return (unsigned int)f2bfu(lo) | ((unsigned int)f2bfu(hi) << 16);
}
__device__ __forceinline__ bf16x8 loadB_sw(const __hip_bfloat16* wsb, int frag, int lane) {
    return *(const bf16x8*)(wsb + (frag << 9) + (lane << 3));
}
__device__ __forceinline__ bf16x8 loadB_f32(const float* wf, int idx) {
    bf16x8 r;
    #pragma unroll
    for (int j = 0; j < 8; ++j) r[j] = (short)f2bfu(wf[idx + j]);
    return r;
}
__device__ __forceinline__ float gelu(float v) {
    return 0.5f * v * (1.f + erff(v * 0.70710678118654752f));
}

// ---------------------------------------------------------------- prep
__global__ __launch_bounds__(256) void prep_kernel(
    const float* __restrict__ qkv_w, const float* __restrict__ proj_w,
    const float* __restrict__ fc1_w, const float* __restrict__ fc2_w,
    const float* __restrict__ rpb,
    __hip_bfloat16* __restrict__ wsb, float* __restrict__ biasM)
{
    int i = blockIdx.x * 256 + threadIdx.x;
    if (i < WS_BF16_N) {
        int f = i >> 9, lane = (i >> 3) & 63, j = i & 7;
        int l15 = lane & 15, g = lane >> 4;
        float v;
        if (f < FR_PROJ) {
            int ks = f % 3, nt = (f / 3) % 6, c = f / 18;
            v = qkv_w[(c * 96 + nt * 16 + l15) * 96 + ks * 32 + g * 8 + j];
            if (c == 0) v *= SCALE;
        } else if (f < FR_FC1) {
            int f2 = f - FR_PROJ, ks = f2 % 3, nt = f2 / 3;
            v = proj_w[(nt * 16 + l15) * 96 + ks * 32 + g * 8 + j];
        } else if (f < FR_FC2) {
            int f2 = f - FR_FC1, ks = f2 % 3, nt = (f2 / 3) % 4, hc = f2 / 12;
            v = fc1_w[(hc * 64 + nt * 16 + l15) * 96 + ks * 32 + g * 8 + j];
        } else {
            int f2 = f - FR_FC2, ks2 = f2 % 2, hc = (f2 / 2) % 6, nt = f2 / 12;
            v = fc2_w[(nt * 16 + l15) * 384 + hc * 64 + ks2 * 32 + g * 8 + j];
        }
        wsb[i] = __float2bfloat16(v);
    } else if (i < WS_BF16_N + 37632) {
        int j = i - WS_BF16_N;
        int r = j & 3, lane = (j >> 2) & 63;
        int rest = j >> 8;
        int U = rest % 7; rest /= 7;
        int Tt = rest % 7, h = rest / 7;
        int t = Tt * 16 + (lane & 15);              if (t > 97) t = 97;
        int u = U * 16 + ((lane >> 4) << 2) + r;    if (u > 97) u = 97;
        biasM[j] = rpb[(pcode(t) - pcode(u) + 253) * 3 + h];
    }
}

// ---------------------------------------------------------------- attention
__global__ __launch_bounds__(512, 4) void attn_kernel(
    const float* __restrict__ x,
    const float* __restrict__ n1w, const float* __restrict__ n1b,
    const float* __restrict__ qkv_w, const float* __restrict__ qkv_b,
    const float* __restrict__ proj_w, const float* __restrict__ proj_b,
    const float* __restrict__ rpb,
    const __hip_bfloat16* __restrict__ wsb, const float* __restrict__ biasM,
    int usews,
    float* __restrict__ out)
{
    __shared__ __align__(16) __hip_bfloat16 XS[112][104];  // LN'd x; later attn-out
    __shared__ __align__(16) __hip_bfloat16 Kb[112][104];
    __shared__ __align__(16) __hip_bfloat16 VQ[13056];     // QB[112][104] then vT[96][136]
    __shared__ int rowbase[NTOK];

    const int wid = blockIdx.x, tid = threadIdx.x;
    const int lane = tid & 63, wv = tid >> 6;
    const int l15 = lane & 15;
    const int g = lane >> 4;
    const int koff = g * 8;
    const int drow = g * 4;

    for (int t = tid; t < NTOK; t += 512) rowbase[t] = row_of(wid, t) * 96;
    for (int i = tid; i < 14 * 104; i += 512) {
        int r = 98 + i / 104, c = i % 104;
        XS[r][c] = __float2bfloat16(0.f);
    }

    // ---- LN1 -> XS bf16 (one wave per token)
    {
        float w0 = n1w[lane], b0 = n1b[lane];
        float w1 = (lane < 32) ? n1w[64 + lane] : 0.f;
        float b1 = (lane < 32) ? n1b[64 + lane] : 0.f;
        for (int t = wv; t < NTOK; t += 8) {
            int base = row_of(wid, t) * 96;
            float v0 = x[base + lane];
            float v1 = (lane < 32) ? x[base + 64 + lane] : 0.f;
            float s = v0 + v1;
            #pragma unroll
            for (int m = 32; m; m >>= 1) s += __shfl_xor(s, m, 64);
            float mean = s * (1.f / 96.f);
            float e0 = v0 - mean;
            float e1 = (lane < 32) ? (v1 - mean) : 0.f;
            float ss = e0 * e0 + e1 * e1;
            #pragma unroll
            for (int m = 32; m; m >>= 1) ss += __shfl_xor(ss, m, 64);
            float rstd = rsqrtf(ss * (1.f / 96.f) + 1e-5f);
            XS[t][lane] = __float2bfloat16(e0 * rstd * w0 + b0);
            if (lane < 32)
                XS[t][64 + lane] = __float2bfloat16(e1 * rstd * w1 + b1);
        }
    }
    __syncthreads();                                   // bar0: XS ready

    // ---- chunk q: Q = XS @ Wq^T, C-frags -> QB bounce
    __hip_bfloat16* QB = &VQ[0];                       // [112][104]
    for (int tile = wv; tile < 42; tile += 8) {
        int m0 = (tile / 6) * 16, nt = tile % 6, n0 = nt * 16;
        f32x4 acc = {0.f, 0.f, 0.f, 0.f};
        #pragma unroll
        for (int ks = 0; ks < 3; ++ks) {
            bf16x8 a = *(const bf16x8*)&XS[m0 + l15][ks * 32 + koff];
            bf16x8 b = usews ? loadB_sw(wsb, nt * 3 + ks, lane)
                             : loadB_f32(qkv_w, (n0 + l15) * 96 + ks * 32 + koff);
            acc = __builtin_amdgcn_mfma_f32_16x16x32_bf16(a, b, acc, 0, 0, 0);
        }
        float bb = qkv_b[n0 + l15];
        #pragma unroll
        for (int r = 0; r < 4; ++r) {
            float q = usews ? (acc[r] + bb * SCALE) : ((acc[r] + bb) * SCALE);
            QB[(m0 + drow + r) * 104 + n0 + l15] = __float2bfloat16(q);
        }
    }
    __syncthreads();                                   // bar1: QB ready

    // ---- Q preload to registers
    bf16x8 qf[3];
    #pragma unroll
    for (int i = 0; i < 3; ++i) {
        int task = wv + 8 * i;
        if (task < 21) {
            int s_ = task / 3, h_ = task - 3 * s_;
            qf[i] = *(const bf16x8*)&QB[(s_ * 16 + l15) * 104 + h_ * 32 + koff];
        }
    }
    __syncthreads();                                   // bar2: QB dead -> vT region

    // ---- vT tail zero + chunks k, v
    __hip_bfloat16* vT = &VQ[0];                       // [96][136]
    for (int i = tid; i < 96 * 38; i += 512) {
        int r = i / 38, c = 98 + (i - r * 38);
        vT[r * 136 + c] = __float2bfloat16(0.f);
    }
    for (int c = 1; c < 3; ++c) {
        for (int tile = wv; tile < 42; tile += 8) {
            int m0 = (tile / 6) * 16, nt = tile % 6, n0 = nt * 16;
            f32x4 acc = {0.f, 0.f, 0.f, 0.f};
            #pragma unroll
            for (int ks = 0; ks < 3; ++ks) {
                bf16x8 a = *(const bf16x8*)&XS[m0 + l15][ks * 32 + koff];
                bf16x8 b = usews ? loadB_sw(wsb, (c * 6 + nt) * 3 + ks, lane)
                                 : loadB_f32(qkv_w + c * 9216,
                                             (n0 + l15) * 96 + ks * 32 + koff);
                acc = __builtin_amdgcn_mfma_f32_16x16x32_bf16(a, b, acc, 0, 0, 0);
            }
            float bb = qkv_b[c * 96 + n0 + l15];
            if (c == 1) {
                #pragma unroll
                for (int r = 0; r < 4; ++r)
                    Kb[m0 + drow + r][n0 + l15] = __float2bfloat16(acc[r] + bb);
            } else {
                unsigned int d0 = pk2(acc[0] + bb, acc[1] + bb);
                unsigned int d1 = pk2(acc[2] + bb, acc[3] + bb);
                int u0 = m0 + drow;
                if (u0 < NTOK) {
                    unsigned int* p = (unsigned int*)&vT[(n0 + l15) * 136 + u0];
                    p[0] = d0;
                    if (u0 + 2 < NTOK) p[1] = d1;
                }
            }
        }
    }
    __syncthreads();                                   // bar3: Kb, vT ready

    // ---- head loop, barrier-free
    const bool oddg = (g >> 1) & 1;
    const int srcA = l15 + ((g & 1) << 5);
    const int srcB = srcA + 16;
    #pragma unroll 1
    for (int i = 0; i < 3; ++i) {
        int task = wv + 8 * i;
        if (task >= 21) break;
        int strip = task / 3, h = task - 3 * strip;

        f32x4 s[7];
        #pragma unroll
        for (int U = 0; U < 7; ++U) {
            bf16x8 ak = *(const bf16x8*)&Kb[U * 16 + l15][h * 32 + koff];
            f32x4 z = {0.f, 0.f, 0.f, 0.f};
            s[U] = __builtin_amdgcn_mfma_f32_16x16x32_bf16(ak, qf[i], z, 0, 0, 0);
        }
        if (usews) {
            const float* bmb = biasM + (((h * 7 + strip) * 7) << 8) + (lane << 2);
            #pragma unroll
            for (int U = 0; U < 7; ++U) {
                f32x4 bv = *(const f32x4*)(bmb + (U << 8));
                s[U][0] += bv[0]; s[U][1] += bv[1]; s[U][2] += bv[2]; s[U][3] += bv[3];
            }
        } else {
            int tq = strip * 16 + l15; if (tq > 97) tq = 97;
            int pt = pcode(tq);
            #pragma unroll
            for (int U = 0; U < 7; ++U)
                #pragma unroll
                for (int r = 0; r < 4; ++r) {
                    int u = U * 16 + drow + r; if (u > 97) u = 97;
                    s[U][r] += rpb[(pt - pcode(u) + 253) * 3 + h];
                }
        }
        if (drow > 0) { s[6][0] = -1e30f; s[6][1] = -1e30f; }
        s[6][2] = -1e30f; s[6][3] = -1e30f;
        f32x4 sumv = {0.f, 0.f, 0.f, 0.f};
        #pragma unroll
        for (int U = 0; U < 7; ++U) {
            #pragma unroll
            for (int r = 0; r < 4; ++r) { s[U][r] = __expf(s[U][r]); sumv[r] += s[U][r]; }
        }
        float hs = sumv[0] + sumv[1] + sumv[2] + sumv[3];
        hs += __shfl_xor(hs, 16, 64);
        hs += __shfl_xor(hs, 32, 64);
        float inv = 1.f / hs;
        unsigned int dwl[7], dwh[7];
        #pragma unroll
        for (int U = 0; U < 7; ++U) {
            dwl[U] = pk2(s[U][0] * inv, s[U][1] * inv);
            dwh[U] = pk2(s[U][2] * inv, s[U][3] * inv);
        }
        f32x4 acc0 = {0.f, 0.f, 0.f, 0.f}, acc1 = {0.f, 0.f, 0.f, 0.f};
        #pragma unroll
        for (int ks = 0; ks < 4; ++ks) {
            unsigned int D0, D1, D2, D3;
            if (ks < 3) {
                unsigned int e0 = __shfl((int)dwl[2 * ks], srcA, 64);
                unsigned int o0 = __shfl((int)dwl[2 * ks + 1], srcA, 64);
                unsigned int e1 = __shfl((int)dwh[2 * ks], srcA, 64);
                unsigned int o1 = __shfl((int)dwh[2 * ks + 1], srcA, 64);
                unsigned int e2 = __shfl((int)dwl[2 * ks], srcB, 64);
                unsigned int o2 = __shfl((int)dwl[2 * ks + 1], srcB, 64);
                unsigned int e3 = __shfl((int)dwh[2 * ks], srcB, 64);
                unsigned int o3 = __shfl((int)dwh[2 * ks + 1], srcB, 64);
                D0 = oddg ? o0 : e0; D1 = oddg ? o1 : e1;
                D2 = oddg ? o2 : e2; D3 = oddg ? o3 : e3;
            } else {
                unsigned int t0 = __shfl((int)dwl[6], srcA, 64);
                unsigned int t1 = __shfl((int)dwh[6], srcA, 64);
                unsigned int t2 = __shfl((int)dwl[6], srcB, 64);
                unsigned int t3 = __shfl((int)dwh[6], srcB, 64);
                D0 = (g < 2) ? t0 : 0u; D1 = (g < 2) ? t1 : 0u;
                D2 = (g < 2) ? t2 : 0u; D3 = (g < 2) ? t3 : 0u;
            }
            union { unsigned int d[4]; bf16x8 v; } af;
            af.d[0] = D0; af.d[1] = D1; af.d[2] = D2; af.d[3] = D3;
            bf16x8 b0 = *(const bf16x8*)&vT[(h * 32 + l15) * 136 + ks * 32 + koff];
            bf16x8 b1 = *(const bf16x8*)&vT[(h * 32 + 16 + l15) * 136 + ks * 32 + koff];
            acc0 = __builtin_amdgcn_mfma_f32_16x16x32_bf16(af.v, b0, acc0, 0, 0, 0);
            acc1 = __builtin_amdgcn_mfma_f32_16x16x32_bf16(af.v, b1, acc1, 0, 0, 0);
        }
        #pragma unroll
        for (int r = 0; r < 4; ++r) {
            XS[strip * 16 + drow + r][h * 32 + l15]      = __float2bfloat16(acc0[r]);
            XS[strip * 16 + drow + r][h * 32 + 16 + l15] = __float2bfloat16(acc1[r]);
        }
    }
    __syncthreads();                                   // bar4: attn-out ready

    // ---- proj GEMM + residual
    for (int tile = wv; tile < 42; tile += 8) {
        int m0 = (tile / 6) * 16, nt = tile % 6, n0 = nt * 16;
        f32x4 acc = {0.f, 0.f, 0.f, 0.f};
        #pragma unroll
        for (int ks = 0; ks < 3; ++ks) {
            bf16x8 a = *(const bf16x8*)&XS[m0 + l15][ks * 32 + koff];
            bf16x8 b = usews ? loadB_sw(wsb, FR_PROJ + nt * 3 + ks, lane)
                             : loadB_f32(proj_w, (n0 + l15) * 96 + ks * 32 + koff);
            acc = __builtin_amdgcn_mfma_f32_16x16x32_bf16(a, b, acc, 0, 0, 0);
        }
        float pb = proj_b[n0 + l15];
        #pragma unroll
        for (int r = 0; r < 4; ++r) {
            int t = m0 + drow + r;
            if (t < NTOK) {
                int idx = rowbase[t] + n0 + l15;
                out[idx] = x[idx] + acc[r] + pb;
            }
        }
    }
}

// ---------------------------------------------------------------- MLP (MFMA)
__global__ __launch_bounds__(256, 3) void mlp_kernel(
    const float* __restrict__ n2w, const float* __restrict__ n2b,
    const float* __restrict__ w1, const float* __restrict__ b1,
    const float* __restrict__ w2, const float* __restrict__ b2,
    const __hip_bfloat16* __restrict__ wsb, int usews,
    float* __restrict__ io)
{
    __shared__ __align__(16) __hip_bfloat16 XS[128][104];   // only LDS: 26.6 KB

    const int tid = threadIdx.x, lane = tid & 63, wv = tid >> 6;
    const int tok0 = blockIdx.x * 128;
    const int l15 = lane & 15;
    const int g = lane >> 4;
    const int koff = g * 8;
    const int drow = g * 4;
    const int m0 = wv * 32;
    const bool oddg = (g >> 1) & 1;
    const int srcA = l15 + ((g & 1) << 5);
    const int srcB = srcA + 16;

    // ---- LN2 -> XS bf16
    for (int t = wv; t < 128; t += 4) {
        int base = (tok0 + t) * 96;
        float v0 = io[base + lane];
        float v1 = (lane < 32) ? io[base + 64 + lane] : 0.f;
        float s = v0 + v1;
        #pragma unroll
        for (int m = 32; m; m >>= 1) s += __shfl_xor(s, m, 64);
        float mean = s * (1.f / 96.f);
        float e0 = v0 - mean;
        float e1 = (lane < 32) ? (v1 - mean) : 0.f;
        float ss = e0 * e0 + e1 * e1;
        #pragma unroll
        for (int m = 32; m; m >>= 1) ss += __shfl_xor(ss, m, 64);
        float rstd = rsqrtf(ss * (1.f / 96.f) + 1e-5f);
        XS[t][lane] = __float2bfloat16(e0 * rstd * n2w[lane] + n2b[lane]);
        if (lane < 32)
            XS[t][64 + lane] = __float2bfloat16(e1 * rstd * n2w[64 + lane] + n2b[64 + lane]);
    }
    __syncthreads();                                   // only barrier

    f32x4 yacc[2][6];
    #pragma unroll
    for (int mt = 0; mt < 2; ++mt)
        #pragma unroll
        for (int nt = 0; nt < 6; ++nt)
            yacc[mt][nt] = (f32x4){0.f, 0.f, 0.f, 0.f};

    #pragma unroll 1
    for (int hc = 0; hc < 6; ++hc) {
        // GEMM1 swapped: C'[hid][tok] = W1[hc] @ XS^T
        f32x4 s_[4][2];
        #pragma unroll
        for (int ht = 0; ht < 4; ++ht)
            #pragma unroll
            for (int tT = 0; tT < 2; ++tT)
                s_[ht][tT] = (f32x4){0.f, 0.f, 0.f, 0.f};
        #pragma unroll
        for (int ks = 0; ks < 3; ++ks) {
            bf16x8 xb0 = *(const bf16x8*)&XS[m0 + l15][ks * 32 + koff];
            bf16x8 xb1 = *(const bf16x8*)&XS[m0 + 16 + l15][ks * 32 + koff];
            #pragma unroll
            for (int ht = 0; ht < 4; ++ht) {
                bf16x8 aw = usews ? loadB_sw(wsb, FR_FC1 + (hc * 4 + ht) * 3 + ks, lane)
                                  : loadB_f32(w1, (hc * 64 + ht * 16 + l15) * 96 + ks * 32 + koff);
                s_[ht][0] = __builtin_amdgcn_mfma_f32_16x16x32_bf16(aw, xb0, s_[ht][0], 0, 0, 0);
                s_[ht][1] = __builtin_amdgcn_mfma_f32_16x16x32_bf16(aw, xb1, s_[ht][1], 0, 0, 0);
            }
        }
        // bias + GELU in-reg, pack to dwords
        unsigned int dwl[4][2], dwh[4][2];
        #pragma unroll
        for (int ht = 0; ht < 4; ++ht) {
            f32x4 bv = *(const f32x4*)&b1[hc * 64 + ht * 16 + drow];
            #pragma unroll
            for (int tT = 0; tT < 2; ++tT) {
                float g0 = gelu(s_[ht][tT][0] + bv[0]);
                float g1 = gelu(s_[ht][tT][1] + bv[1]);
                float g2 = gelu(s_[ht][tT][2] + bv[2]);
                float g3 = gelu(s_[ht][tT][3] + bv[3]);
                dwl[ht][tT] = pk2(g0, g1);
                dwh[ht][tT] = pk2(g2, g3);
            }
        }
        // GEMM2: Y[tok][out] += H @ W2^T ; A-frags via shfl transform
        #pragma unroll
        for (int ks2 = 0; ks2 < 2; ++ks2) {
            union { unsigned int d[4]; bf16x8 v; } af[2];
            #pragma unroll
            for (int tT = 0; tT < 2; ++tT) {
                unsigned int e0 = __shfl((int)dwl[2 * ks2][tT], srcA, 64);
                unsigned int o0 = __shfl((int)dwl[2 * ks2 + 1][tT], srcA, 64);
                unsigned int e1 = __shfl((int)dwh[2 * ks2][tT], srcA, 64);
                unsigned int o1 = __shfl((int)dwh[2 * ks2 + 1][tT], srcA, 64);
                unsigned int e2 = __shfl((int)dwl[2 * ks2][tT], srcB, 64);
                unsigned int o2 = __shfl((int)dwl[2 * ks2 + 1][tT], srcB, 64);
                unsigned int e3 = __shfl((int)dwh[2 * ks2][tT], srcB, 64);
                unsigned int o3 = __shfl((int)dwh[2 * ks2 + 1][tT], srcB, 64);
                af[tT].d[0] = oddg ? o0 : e0;
                af[tT].d[1] = oddg ? o1 : e1;
                af[tT].d[2] = oddg ? o2 : e2;
                af[tT].d[3] = oddg ? o3 : e3;
            }
            #pragma unroll
            for (int nt = 0; nt < 6; ++nt) {
                bf16x8 bw = usews ? loadB_sw(wsb, FR_FC2 + (nt * 6 + hc) * 2 + ks2, lane)
                                  : loadB_f32(w2, (nt * 16 + l15) * 384 + hc * 64 + ks2 * 32 + koff);
                yacc[0][nt] = __builtin_amdgcn_mfma_f32_16x16x32_bf16(af[0].v, bw, yacc[0][nt], 0, 0, 0);
                yacc[1][nt] = __builtin_amdgcn_mfma_f32_16x16x32_bf16(af[1].v, bw, yacc[1][nt], 0, 0, 0);
            }
        }
    }

    // ---- epilogue: residual + fc2 bias
    #pragma unroll
    for (int mt = 0; mt < 2; ++mt)
        #pragma unroll
        for (int nt = 0; nt < 6; ++nt)
            #pragma unroll
            for (int r = 0; r < 4; ++r) {
                int t = tok0 + m0 + mt * 16 + drow + r;
                int c = nt * 16 + l15;
                int idx = t * 96 + c;
                io[idx] = io[idx] + yacc[mt][nt][r] + b2[c];
            }
}

extern "C" void kernel_launch(void* const* d_in, const int* in_sizes, int n_in,
                              void* d_out, int out_size, void* d_ws, size_t ws_size,
                              hipStream_t stream) {
    const float* x      = (const float*)d_in[0];
    const float* n1w    = (const float*)d_in[1];
    const float* n1b    = (const float*)d_in[2];
    const float* qkv_w  = (const float*)d_in[3];
    const float* qkv_b  = (const float*)d_in[4];
    const float* proj_w = (const float*)d_in[5];
    const float* proj_b = (const float*)d_in[6];
    const float* rpb    = (const float*)d_in[7];
    const float* n2w    = (const float*)d_in[8];
    const float* n2b    = (const float*)d_in[9];
    const float* fc1_w  = (const float*)d_in[10];
    const float* fc1_b  = (const float*)d_in[11];
    const float* fc2_w  = (const float*)d_in[12];
    const float* fc2_b  = (const float*)d_in[13];
    float* out = (float*)d_out;

    const int usews = (ws_size >= (size_t)WS_NEED) ? 1 : 0;
    __hip_bfloat16* wsb = (__hip_bfloat16*)d_ws;
    float* biasM = (float*)((char*)d_ws + WS_BIASM_BYTE);

    if (usews)
        prep_kernel<<<(WS_BF16_N + 37632 + 255) / 256, 256, 0, stream>>>(
            qkv_w, proj_w, fc1_w, fc2_w, rpb, wsb, biasM);

    attn_kernel<<<2048, 512, 0, stream>>>(x, n1w, n1b, qkv_w, qkv_b,
                                          proj_w, proj_b, rpb,
                                          wsb, biasM, usews, out);
    mlp_kernel<<<1568, 256, 0, stream>>>(n2w, n2b, fc1_w, fc1_b, fc2_w, fc2_b,
                                         wsb, usews, out);
}

// Round 7
// 485.683 us; speedup vs baseline: 1.0181x; 1.0181x over previous
//
#include <hip/hip_runtime.h>
#include <hip/hip_bf16.h>
#include <math.h>

// Swin Transformer 3D block, MI355X (gfx950).  R7: FULLY FUSED.
// prep_kernel: fragment-linear bf16 weights in d_ws (Q-scale folded) +
//   rel-pos bias in swapped score C-fragment layout.
// fused_kernel (448 thr = 7 waves, per window):
//   LN1 -> QKV GEMMs -> swapped scores + reg softmax + shfl P->A -> PV ->
//   proj (per-strip) -> residual in regs -> LN2 in regs -> MLP GEMM1-swapped
//   -> GELU -> shfl transform -> GEMM2 -> residual -> coalesced store via
//   fp32 LDS bounce (overlaid on dead K/V region).
//   Residual stream stays fp32 end-to-end. 6 barriers/block.

#define NTOK 98
#define SCALE 0.17677669529663687f

// fragment ids (x512 elems): qkv 0..53, proj 54..71, fc1 72..143, fc2 144..215
#define FR_PROJ 54
#define FR_FC1  72
#define FR_FC2  144
#define WS_BF16_N 110592
#define WS_BIASM_BYTE 221184
#define WS_NEED   371712

typedef __attribute__((ext_vector_type(8))) short bf16x8;
typedef __attribute__((ext_vector_type(4))) float f32x4;

__device__ __forceinline__ int row_of(int wid, int t) {
    int b = wid >> 8, rem = wid & 255;
    int d0 = rem >> 6, h0 = (rem >> 3) & 7, w0 = rem & 7;
    int td = t / 49, tr = t % 49, th = tr / 7, tw = tr % 7;
    int dd = d0 * 2 + td, hh = h0 * 7 + th, ww = w0 * 7 + tw;
    return ((b * 8 + dd) * 56 + hh) * 56 + ww;
}

__device__ __forceinline__ int pcode(int t) {
    int a = t / 49, r = t - 49 * a, b = r / 7, c = r - 7 * b;
    return a * 169 + b * 13 + c;
}

__device__ __forceinline__ unsigned short f2bfu(float f) {
    __hip_bfloat16 h = __float2bfloat16(f);
    unsigned short u; __builtin_memcpy(&u, &h, 2); return u;
}
__device__ __forceinline__ unsigned int pk2(float lo, float hi) {
    return (unsigned int)f2bfu(lo) | ((unsigned int)f2bfu(hi) << 16);
}
__device__ __forceinline__ bf16x8 loadB_sw(const __hip_bfloat16* wsb, int frag, int lane) {
    return *(const bf16x8*)(wsb + (frag << 9) + (lane << 3));
}
__device__ __forceinline__ bf16x8 loadB_f32(const float* wf, int idx) {
    bf16x8 r;
    #pragma unroll
    for (int j = 0; j < 8; ++j) r[j] = (short)f2bfu(wf[idx + j]);
    return r;
}
__device__ __forceinline__ float gelu(float v) {
    return 0.5f * v * (1.f + erff(v * 0.70710678118654752f));
}

// ---------------------------------------------------------------- prep
__global__ __launch_bounds__(256) void prep_kernel(
    const float* __restrict__ qkv_w, const float* __restrict__ proj_w,
    const float* __restrict__ fc1_w, const float* __restrict__ fc2_w,
    const float* __restrict__ rpb,
    __hip_bfloat16* __restrict__ wsb, float* __restrict__ biasM)
{
    int i = blockIdx.x * 256 + threadIdx.x;
    if (i < WS_BF16_N) {
        int f = i >> 9, lane = (i >> 3) & 63, j = i & 7;
        int l15 = lane & 15, g = lane >> 4;
        float v;
        if (f < FR_PROJ) {
            int ks = f % 3, nt = (f / 3) % 6, c = f / 18;
            v = qkv_w[(c * 96 + nt * 16 + l15) * 96 + ks * 32 + g * 8 + j];
            if (c == 0) v *= SCALE;
        } else if (f < FR_FC1) {
            int f2 = f - FR_PROJ, ks = f2 % 3, nt = f2 / 3;
            v = proj_w[(nt * 16 + l15) * 96 + ks * 32 + g * 8 + j];
        } else if (f < FR_FC2) {
            int f2 = f - FR_FC1, ks = f2 % 3, nt = (f2 / 3) % 4, hc = f2 / 12;
            v = fc1_w[(hc * 64 + nt * 16 + l15) * 96 + ks * 32 + g * 8 + j];
        } else {
            int f2 = f - FR_FC2, ks2 = f2 % 2, hc = (f2 / 2) % 6, nt = f2 / 12;
            v = fc2_w[(nt * 16 + l15) * 384 + hc * 64 + ks2 * 32 + g * 8 + j];
        }
        wsb[i] = __float2bfloat16(v);
    } else if (i < WS_BF16_N + 37632) {
        int j = i - WS_BF16_N;
        int r = j & 3, lane = (j >> 2) & 63;
        int rest = j >> 8;
        int U = rest % 7; rest /= 7;
        int Tt = rest % 7, h = rest / 7;
        int t = Tt * 16 + (lane & 15);              if (t > 97) t = 97;
        int u = U * 16 + ((lane >> 4) << 2) + r;    if (u > 97) u = 97;
        biasM[j] = rpb[(pcode(t) - pcode(u) + 253) * 3 + h];
    }
}

// ---------------------------------------------------------------- fused block
__global__ __launch_bounds__(448, 4) void fused_kernel(
    const float* __restrict__ x,
    const float* __restrict__ n1w, const float* __restrict__ n1b,
    const float* __restrict__ qkv_w, const float* __restrict__ qkv_b,
    const float* __restrict__ proj_w, const float* __restrict__ proj_b,
    const float* __restrict__ rpb,
    const float* __restrict__ n2w, const float* __restrict__ n2b,
    const float* __restrict__ w1, const float* __restrict__ b1,
    const float* __restrict__ w2, const float* __restrict__ b2,
    const __hip_bfloat16* __restrict__ wsb, const float* __restrict__ biasM,
    int usews,
    float* __restrict__ out)
{
    // LDS carve: [0,23296) XS bf16[112][104]; [23296,46592) Kb bf16[112][104];
    // [46592,72704) VQ bf16[13056] (QB[112][104] then vT[96][136]);
    // OutF fp32[112][100] overlays [23296, 68096) after attn phases are done.
    __shared__ __align__(16) unsigned char LB[72704];
    __shared__ int rowbase[NTOK];
    __hip_bfloat16 (*XS)[104] = (__hip_bfloat16 (*)[104])LB;
    __hip_bfloat16 (*Kb)[104] = (__hip_bfloat16 (*)[104])(LB + 23296);
    __hip_bfloat16* VQ = (__hip_bfloat16*)(LB + 46592);
    float* OutF = (float*)(LB + 23296);

    const int wid = blockIdx.x, tid = threadIdx.x;
    const int lane = tid & 63, wv = tid >> 6;       // 7 waves
    const int l15 = lane & 15;
    const int g = lane >> 4;
    const int koff = g * 8;
    const int drow = g * 4;
    const bool oddg = (g >> 1) & 1;
    const int srcA = l15 + ((g & 1) << 5);
    const int srcB = srcA + 16;

    for (int t = tid; t < NTOK; t += 448) rowbase[t] = row_of(wid, t) * 96;
    for (int i = tid; i < 14 * 104; i += 448) {     // zero XS pad rows 98..111
        int r = 98 + i / 104, c = i % 104;
        XS[r][c] = __float2bfloat16(0.f);
    }

    // ---- LN1 -> XS bf16 (one wave per token)
    {
        float w0 = n1w[lane], b0 = n1b[lane];
        float w1_ = (lane < 32) ? n1w[64 + lane] : 0.f;
        float b1_ = (lane < 32) ? n1b[64 + lane] : 0.f;
        for (int t = wv; t < NTOK; t += 7) {
            int base = row_of(wid, t) * 96;
            float v0 = x[base + lane];
            float v1 = (lane < 32) ? x[base + 64 + lane] : 0.f;
            float s = v0 + v1;
            #pragma unroll
            for (int m = 32; m; m >>= 1) s += __shfl_xor(s, m, 64);
            float mean = s * (1.f / 96.f);
            float e0 = v0 - mean;
            float e1 = (lane < 32) ? (v1 - mean) : 0.f;
            float ss = e0 * e0 + e1 * e1;
            #pragma unroll
            for (int m = 32; m; m >>= 1) ss += __shfl_xor(ss, m, 64);
            float rstd = rsqrtf(ss * (1.f / 96.f) + 1e-5f);
            XS[t][lane] = __float2bfloat16(e0 * rstd * w0 + b0);
            if (lane < 32)
                XS[t][64 + lane] = __float2bfloat16(e1 * rstd * w1_ + b1_);
        }
    }
    __syncthreads();                                   // bar0: XS ready

    // ---- chunk q: Q = XS @ Wq^T, C-frags -> QB bounce
    __hip_bfloat16* QB = &VQ[0];                       // [112][104]
    for (int tile = wv; tile < 42; tile += 7) {
        int m0 = (tile / 6) * 16, nt = tile % 6, n0 = nt * 16;
        f32x4 acc = {0.f, 0.f, 0.f, 0.f};
        #pragma unroll
        for (int ks = 0; ks < 3; ++ks) {
            bf16x8 a = *(const bf16x8*)&XS[m0 + l15][ks * 32 + koff];
            bf16x8 b = usews ? loadB_sw(wsb, nt * 3 + ks, lane)
                             : loadB_f32(qkv_w, (n0 + l15) * 96 + ks * 32 + koff);
            acc = __builtin_amdgcn_mfma_f32_16x16x32_bf16(a, b, acc, 0, 0, 0);
        }
        float bb = qkv_b[n0 + l15];
        #pragma unroll
        for (int r = 0; r < 4; ++r) {
            float q = usews ? (acc[r] + bb * SCALE) : ((acc[r] + bb) * SCALE);
            QB[(m0 + drow + r) * 104 + n0 + l15] = __float2bfloat16(q);
        }
    }
    __syncthreads();                                   // bar1: QB ready

    // ---- Q preload to registers (3 tasks per wave, exact)
    bf16x8 qf[3];
    #pragma unroll
    for (int i = 0; i < 3; ++i) {
        int task = wv + 7 * i;
        int s_ = task / 3, h_ = task - 3 * s_;
        qf[i] = *(const bf16x8*)&QB[(s_ * 16 + l15) * 104 + h_ * 32 + koff];
    }
    __syncthreads();                                   // bar2: QB dead -> vT region

    // ---- vT tail zero + chunks k, v
    __hip_bfloat16* vT = &VQ[0];                       // [96][136]
    for (int i = tid; i < 96 * 38; i += 448) {
        int r = i / 38, c = 98 + (i - r * 38);
        vT[r * 136 + c] = __float2bfloat16(0.f);
    }
    for (int c = 1; c < 3; ++c) {
        for (int tile = wv; tile < 42; tile += 7) {
            int m0 = (tile / 6) * 16, nt = tile % 6, n0 = nt * 16;
            f32x4 acc = {0.f, 0.f, 0.f, 0.f};
            #pragma unroll
            for (int ks = 0; ks < 3; ++ks) {
                bf16x8 a = *(const bf16x8*)&XS[m0 + l15][ks * 32 + koff];
                bf16x8 b = usews ? loadB_sw(wsb, (c * 6 + nt) * 3 + ks, lane)
                                 : loadB_f32(qkv_w + c * 9216,
                                             (n0 + l15) * 96 + ks * 32 + koff);
                acc = __builtin_amdgcn_mfma_f32_16x16x32_bf16(a, b, acc, 0, 0, 0);
            }
            float bb = qkv_b[c * 96 + n0 + l15];
            if (c == 1) {
                #pragma unroll
                for (int r = 0; r < 4; ++r)
                    Kb[m0 + drow + r][n0 + l15] = __float2bfloat16(acc[r] + bb);
            } else {
                unsigned int d0 = pk2(acc[0] + bb, acc[1] + bb);
                unsigned int d1 = pk2(acc[2] + bb, acc[3] + bb);
                int u0 = m0 + drow;
                if (u0 < NTOK) {
                    unsigned int* p = (unsigned int*)&vT[(n0 + l15) * 136 + u0];
                    p[0] = d0;
                    if (u0 + 2 < NTOK) p[1] = d1;
                }
            }
        }
    }
    __syncthreads();                                   // bar3: Kb, vT ready

    // ---- head loop, barrier-free: 3 (strip,head) tasks per wave
    #pragma unroll 1
    for (int i = 0; i < 3; ++i) {
        int task = wv + 7 * i;
        int strip = task / 3, h = task - 3 * strip;

        f32x4 s[7];
        #pragma unroll
        for (int U = 0; U < 7; ++U) {
            bf16x8 ak = *(const bf16x8*)&Kb[U * 16 + l15][h * 32 + koff];
            f32x4 z = {0.f, 0.f, 0.f, 0.f};
            s[U] = __builtin_amdgcn_mfma_f32_16x16x32_bf16(ak, qf[i], z, 0, 0, 0);
        }
        if (usews) {
            const float* bmb = biasM + (((h * 7 + strip) * 7) << 8) + (lane << 2);
            #pragma unroll
            for (int U = 0; U < 7; ++U) {
                f32x4 bv = *(const f32x4*)(bmb + (U << 8));
                s[U][0] += bv[0]; s[U][1] += bv[1]; s[U][2] += bv[2]; s[U][3] += bv[3];
            }
        } else {
            int tq = strip * 16 + l15; if (tq > 97) tq = 97;
            int pt = pcode(tq);
            #pragma unroll
            for (int U = 0; U < 7; ++U)
                #pragma unroll
                for (int r = 0; r < 4; ++r) {
                    int u = U * 16 + drow + r; if (u > 97) u = 97;
                    s[U][r] += rpb[(pt - pcode(u) + 253) * 3 + h];
                }
        }
        if (drow > 0) { s[6][0] = -1e30f; s[6][1] = -1e30f; }
        s[6][2] = -1e30f; s[6][3] = -1e30f;
        f32x4 sumv = {0.f, 0.f, 0.f, 0.f};
        #pragma unroll
        for (int U = 0; U < 7; ++U) {
            #pragma unroll
            for (int r = 0; r < 4; ++r) { s[U][r] = __expf(s[U][r]); sumv[r] += s[U][r]; }
        }
        float hs = sumv[0] + sumv[1] + sumv[2] + sumv[3];
        hs += __shfl_xor(hs, 16, 64);
        hs += __shfl_xor(hs, 32, 64);
        float inv = 1.f / hs;
        unsigned int dwl[7], dwh[7];
        #pragma unroll
        for (int U = 0; U < 7; ++U) {
            dwl[U] = pk2(s[U][0] * inv, s[U][1] * inv);
            dwh[U] = pk2(s[U][2] * inv, s[U][3] * inv);
        }
        f32x4 acc0 = {0.f, 0.f, 0.f, 0.f}, acc1 = {0.f, 0.f, 0.f, 0.f};
        #pragma unroll
        for (int ks = 0; ks < 4; ++ks) {
            unsigned int D0, D1, D2, D3;
            if (ks < 3) {
                unsigned int e0 = __shfl((int)dwl[2 * ks], srcA, 64);
                unsigned int o0 = __shfl((int)dwl[2 * ks + 1], srcA, 64);
                unsigned int e1 = __shfl((int)dwh[2 * ks], srcA, 64);
                unsigned int o1 = __shfl((int)dwh[2 * ks + 1], srcA, 64);
                unsigned int e2 = __shfl((int)dwl[2 * ks], srcB, 64);
                unsigned int o2 = __shfl((int)dwl[2 * ks + 1], srcB, 64);
                unsigned int e3 = __shfl((int)dwh[2 * ks], srcB, 64);
                unsigned int o3 = __shfl((int)dwh[2 * ks + 1], srcB, 64);
                D0 = oddg ? o0 : e0; D1 = oddg ? o1 : e1;
                D2 = oddg ? o2 : e2; D3 = oddg ? o3 : e3;
            } else {
                unsigned int t0 = __shfl((int)dwl[6], srcA, 64);
                unsigned int t1 = __shfl((int)dwh[6], srcA, 64);
                unsigned int t2 = __shfl((int)dwl[6], srcB, 64);
                unsigned int t3 = __shfl((int)dwh[6], srcB, 64);
                D0 = (g < 2) ? t0 : 0u; D1 = (g < 2) ? t1 : 0u;
                D2 = (g < 2) ? t2 : 0u; D3 = (g < 2) ? t3 : 0u;
            }
            union { unsigned int d[4]; bf16x8 v; } af;
            af.d[0] = D0; af.d[1] = D1; af.d[2] = D2; af.d[3] = D3;
            bf16x8 b0 = *(const bf16x8*)&vT[(h * 32 + l15) * 136 + ks * 32 + koff];
            bf16x8 b1_ = *(const bf16x8*)&vT[(h * 32 + 16 + l15) * 136 + ks * 32 + koff];
            acc0 = __builtin_amdgcn_mfma_f32_16x16x32_bf16(af.v, b0, acc0, 0, 0, 0);
            acc1 = __builtin_amdgcn_mfma_f32_16x16x32_bf16(af.v, b1_, acc1, 0, 0, 0);
        }
        #pragma unroll
        for (int r = 0; r < 4; ++r) {
            XS[strip * 16 + drow + r][h * 32 + l15]      = __float2bfloat16(acc0[r]);
            XS[strip * 16 + drow + r][h * 32 + 16 + l15] = __float2bfloat16(acc1[r]);
        }
    }
    __syncthreads();                                   // bar4: attn-out ready; Kb/vT dead

    // ==== per-strip tail: proj -> residual(fp32 regs) -> LN2(regs) -> MLP ====
    {
        const int strip = wv, m0 = strip * 16;

        // proj GEMM (strip-private A) + x residual into registers
        float res[6][4];
        #pragma unroll
        for (int nt = 0; nt < 6; ++nt) {
            f32x4 acc = {0.f, 0.f, 0.f, 0.f};
            #pragma unroll
            for (int ks = 0; ks < 3; ++ks) {
                bf16x8 a = *(const bf16x8*)&XS[m0 + l15][ks * 32 + koff];
                bf16x8 b = usews ? loadB_sw(wsb, FR_PROJ + nt * 3 + ks, lane)
                                 : loadB_f32(proj_w, (nt * 16 + l15) * 96 + ks * 32 + koff);
                acc = __builtin_amdgcn_mfma_f32_16x16x32_bf16(a, b, acc, 0, 0, 0);
            }
            float pb = proj_b[nt * 16 + l15];
            #pragma unroll
            for (int r = 0; r < 4; ++r) {
                int t = m0 + drow + r;
                res[nt][r] = (t < NTOK) ? (acc[r] + pb + x[rowbase[t] + nt * 16 + l15])
                                        : 0.f;
            }
        }

        // LN2 in registers (row stats via 6 in-lane adds + shfl over l15 group),
        // normalized values -> XS (wave-private rows; no barrier needed)
        #pragma unroll
        for (int r = 0; r < 4; ++r) {
            float s = 0.f, sq = 0.f;
            #pragma unroll
            for (int nt = 0; nt < 6; ++nt) { s += res[nt][r]; sq += res[nt][r] * res[nt][r]; }
            #pragma unroll
            for (int m = 1; m < 16; m <<= 1) {
                s  += __shfl_xor(s, m, 64);
                sq += __shfl_xor(sq, m, 64);
            }
            float mean = s * (1.f / 96.f);
            float var  = sq * (1.f / 96.f) - mean * mean;
            float rstd = rsqrtf(var + 1e-5f);
            #pragma unroll
            for (int nt = 0; nt < 6; ++nt) {
                int cc = nt * 16 + l15;
                XS[m0 + drow + r][cc] =
                    __float2bfloat16((res[nt][r] - mean) * rstd * n2w[cc] + n2b[cc]);
            }
        }

        // MLP: GEMM1 swapped -> GELU -> shfl transform -> GEMM2
        f32x4 yacc[6];
        #pragma unroll
        for (int nt = 0; nt < 6; ++nt) yacc[nt] = (f32x4){0.f, 0.f, 0.f, 0.f};

        #pragma unroll 1
        for (int hc = 0; hc < 6; ++hc) {
            f32x4 s_[4];
            #pragma unroll
            for (int ht = 0; ht < 4; ++ht) s_[ht] = (f32x4){0.f, 0.f, 0.f, 0.f};
            #pragma unroll
            for (int ks = 0; ks < 3; ++ks) {
                bf16x8 xb = *(const bf16x8*)&XS[m0 + l15][ks * 32 + koff];
                #pragma unroll
                for (int ht = 0; ht < 4; ++ht) {
                    bf16x8 aw = usews ? loadB_sw(wsb, FR_FC1 + (hc * 4 + ht) * 3 + ks, lane)
                                      : loadB_f32(w1, (hc * 64 + ht * 16 + l15) * 96 + ks * 32 + koff);
                    s_[ht] = __builtin_amdgcn_mfma_f32_16x16x32_bf16(aw, xb, s_[ht], 0, 0, 0);
                }
            }
            unsigned int dwl[4], dwh[4];
            #pragma unroll
            for (int ht = 0; ht < 4; ++ht) {
                f32x4 bv = *(const f32x4*)&b1[hc * 64 + ht * 16 + drow];
                float g0 = gelu(s_[ht][0] + bv[0]);
                float g1 = gelu(s_[ht][1] + bv[1]);
                float g2 = gelu(s_[ht][2] + bv[2]);
                float g3 = gelu(s_[ht][3] + bv[3]);
                dwl[ht] = pk2(g0, g1);
                dwh[ht] = pk2(g2, g3);
            }
            #pragma unroll
            for (int ks2 = 0; ks2 < 2; ++ks2) {
                unsigned int e0 = __shfl((int)dwl[2 * ks2], srcA, 64);
                unsigned int o0 = __shfl((int)dwl[2 * ks2 + 1], srcA, 64);
                unsigned int e1 = __shfl((int)dwh[2 * ks2], srcA, 64);
                unsigned int o1 = __shfl((int)dwh[2 * ks2 + 1], srcA, 64);
                unsigned int e2 = __shfl((int)dwl[2 * ks2], srcB, 64);
                unsigned int o2 = __shfl((int)dwl[2 * ks2 + 1], srcB, 64);
                unsigned int e3 = __shfl((int)dwh[2 * ks2], srcB, 64);
                unsigned int o3 = __shfl((int)dwh[2 * ks2 + 1], srcB, 64);
                union { unsigned int d[4]; bf16x8 v; } af;
                af.d[0] = oddg ? o0 : e0;
                af.d[1] = oddg ? o1 : e1;
                af.d[2] = oddg ? o2 : e2;
                af.d[3] = oddg ? o3 : e3;
                #pragma unroll
                for (int nt = 0; nt < 6; ++nt) {
                    bf16x8 bw = usews ? loadB_sw(wsb, FR_FC2 + (nt * 6 + hc) * 2 + ks2, lane)
                                      : loadB_f32(w2, (nt * 16 + l15) * 384 + hc * 64 + ks2 * 32 + koff);
                    yacc[nt] = __builtin_amdgcn_mfma_f32_16x16x32_bf16(af.v, bw, yacc[nt], 0, 0, 0);
                }
            }
        }

        // final residual + fc2 bias -> OutF (fp32, stride 100)
        #pragma unroll
        for (int nt = 0; nt < 6; ++nt) {
            float bb2 = b2[nt * 16 + l15];
            #pragma unroll
            for (int r = 0; r < 4; ++r) {
                int t = m0 + drow + r;
                OutF[t * 100 + nt * 16 + l15] = res[nt][r] + yacc[nt][r] + bb2;
            }
        }
    }
    __syncthreads();                                   // bar5: OutF complete

    // ---- coalesced store (full 384B rows as f32x4)
    for (int j = tid; j < NTOK * 24; j += 448) {
        int row = j / 24, q = j - row * 24;
        *(f32x4*)&out[rowbase[row] + q * 4] = *(const f32x4*)&OutF[row * 100 + q * 4];
    }
}

extern "C" void kernel_launch(void* const* d_in, const int* in_sizes, int n_in,
                              void* d_out, int out_size, void* d_ws, size_t ws_size,
                              hipStream_t stream) {
    const float* x      = (const float*)d_in[0];
    const float* n1w    = (const float*)d_in[1];
    const float* n1b    = (const float*)d_in[2];
    const float* qkv_w  = (const float*)d_in[3];
    const float* qkv_b  = (const float*)d_in[4];
    const float* proj_w = (const float*)d_in[5];
    const float* proj_b = (const float*)d_in[6];
    const float* rpb    = (const float*)d_in[7];
    const float* n2w    = (const float*)d_in[8];
    const float* n2b    = (const float*)d_in[9];
    const float* fc1_w  = (const float*)d_in[10];
    const float* fc1_b  = (const float*)d_in[11];
    const float* fc2_w  = (const float*)d_in[12];
    const float* fc2_b  = (const float*)d_in[13];
    float* out = (float*)d_out;

    const int usews = (ws_size >= (size_t)WS_NEED) ? 1 : 0;
    __hip_bfloat16* wsb = (__hip_bfloat16*)d_ws;
    float* biasM = (float*)((char*)d_ws + WS_BIASM_BYTE);

    if (usews)
        prep_kernel<<<(WS_BF16_N + 37632 + 255) / 256, 256, 0, stream>>>(
            qkv_w, proj_w, fc1_w, fc2_w, rpb, wsb, biasM);

    fused_kernel<<<2048, 448, 0, stream>>>(x, n1w, n1b, qkv_w, qkv_b,
                                           proj_w, proj_b, rpb,
                                           n2w, n2b, fc1_w, fc1_b, fc2_w, fc2_b,
                                           wsb, biasM, usews, out);
}

// Round 8
// 328.050 us; speedup vs baseline: 1.5072x; 1.4805x over previous
//
#include <hip/hip_runtime.h>
#include <hip/hip_bf16.h>
#include <math.h>

// Swin Transformer 3D block, MI355X (gfx950).  R8: fused, spill-free.
// Changes vs R7: 512 threads / __launch_bounds__(512,4) (2 blocks/CU, VGPR<=128),
// residual kept in LDS OutF (not regs) through the MLP, GEMM1 in two ht-pairs.
// Same verified math as R7 (absmax 0.03125).

#define NTOK 98
#define SCALE 0.17677669529663687f

#define FR_PROJ 54
#define FR_FC1  72
#define FR_FC2  144
#define WS_BF16_N 110592
#define WS_BIASM_BYTE 221184
#define WS_NEED   371712

typedef __attribute__((ext_vector_type(8))) short bf16x8;
typedef __attribute__((ext_vector_type(4))) float f32x4;

__device__ __forceinline__ int row_of(int wid, int t) {
    int b = wid >> 8, rem = wid & 255;
    int d0 = rem >> 6, h0 = (rem >> 3) & 7, w0 = rem & 7;
    int td = t / 49, tr = t % 49, th = tr / 7, tw = tr % 7;
    int dd = d0 * 2 + td, hh = h0 * 7 + th, ww = w0 * 7 + tw;
    return ((b * 8 + dd) * 56 + hh) * 56 + ww;
}

__device__ __forceinline__ int pcode(int t) {
    int a = t / 49, r = t - 49 * a, b = r / 7, c = r - 7 * b;
    return a * 169 + b * 13 + c;
}

__device__ __forceinline__ unsigned short f2bfu(float f) {
    __hip_bfloat16 h = __float2bfloat16(f);
    unsigned short u; __builtin_memcpy(&u, &h, 2); return u;
}
__device__ __forceinline__ unsigned int pk2(float lo, float hi) {
    return (unsigned int)f2bfu(lo) | ((unsigned int)f2bfu(hi) << 16);
}
__device__ __forceinline__ bf16x8 loadB_sw(const __hip_bfloat16* wsb, int frag, int lane) {
    return *(const bf16x8*)(wsb + (frag << 9) + (lane << 3));
}
__device__ __forceinline__ bf16x8 loadB_f32(const float* wf, int idx) {
    bf16x8 r;
    #pragma unroll
    for (int j = 0; j < 8; ++j) r[j] = (short)f2bfu(wf[idx + j]);
    return r;
}
__device__ __forceinline__ float gelu(float v) {
    return 0.5f * v * (1.f + erff(v * 0.70710678118654752f));
}

// ---------------------------------------------------------------- prep
__global__ __launch_bounds__(256) void prep_kernel(
    const float* __restrict__ qkv_w, const float* __restrict__ proj_w,
    const float* __restrict__ fc1_w, const float* __restrict__ fc2_w,
    const float* __restrict__ rpb,
    __hip_bfloat16* __restrict__ wsb, float* __restrict__ biasM)
{
    int i = blockIdx.x * 256 + threadIdx.x;
    if (i < WS_BF16_N) {
        int f = i >> 9, lane = (i >> 3) & 63, j = i & 7;
        int l15 = lane & 15, g = lane >> 4;
        float v;
        if (f < FR_PROJ) {
            int ks = f % 3, nt = (f / 3) % 6, c = f / 18;
            v = qkv_w[(c * 96 + nt * 16 + l15) * 96 + ks * 32 + g * 8 + j];
            if (c == 0) v *= SCALE;
        } else if (f < FR_FC1) {
            int f2 = f - FR_PROJ, ks = f2 % 3, nt = f2 / 3;
            v = proj_w[(nt * 16 + l15) * 96 + ks * 32 + g * 8 + j];
        } else if (f < FR_FC2) {
            int f2 = f - FR_FC1, ks = f2 % 3, nt = (f2 / 3) % 4, hc = f2 / 12;
            v = fc1_w[(hc * 64 + nt * 16 + l15) * 96 + ks * 32 + g * 8 + j];
        } else {
            int f2 = f - FR_FC2, ks2 = f2 % 2, hc = (f2 / 2) % 6, nt = f2 / 12;
            v = fc2_w[(nt * 16 + l15) * 384 + hc * 64 + ks2 * 32 + g * 8 + j];
        }
        wsb[i] = __float2bfloat16(v);
    } else if (i < WS_BF16_N + 37632) {
        int j = i - WS_BF16_N;
        int r = j & 3, lane = (j >> 2) & 63;
        int rest = j >> 8;
        int U = rest % 7; rest /= 7;
        int Tt = rest % 7, h = rest / 7;
        int t = Tt * 16 + (lane & 15);              if (t > 97) t = 97;
        int u = U * 16 + ((lane >> 4) << 2) + r;    if (u > 97) u = 97;
        biasM[j] = rpb[(pcode(t) - pcode(u) + 253) * 3 + h];
    }
}

// ---------------------------------------------------------------- fused block
__global__ __launch_bounds__(512, 4) void fused_kernel(
    const float* __restrict__ x,
    const float* __restrict__ n1w, const float* __restrict__ n1b,
    const float* __restrict__ qkv_w, const float* __restrict__ qkv_b,
    const float* __restrict__ proj_w, const float* __restrict__ proj_b,
    const float* __restrict__ rpb,
    const float* __restrict__ n2w, const float* __restrict__ n2b,
    const float* __restrict__ w1, const float* __restrict__ b1,
    const float* __restrict__ w2, const float* __restrict__ b2,
    const __hip_bfloat16* __restrict__ wsb, const float* __restrict__ biasM,
    int usews,
    float* __restrict__ out)
{
    // LDS carve: [0,23296) XS bf16[112][104]; [23296,46592) Kb bf16[112][104];
    // [46592,72704) VQ bf16[13056] (QB[112][104] then vT[96][136]);
    // OutF fp32[112][100] overlays [23296,68096) after bar4 (Kb/vT dead).
    __shared__ __align__(16) unsigned char LB[72704];
    __shared__ int rowbase[NTOK];
    __hip_bfloat16 (*XS)[104] = (__hip_bfloat16 (*)[104])LB;
    __hip_bfloat16 (*Kb)[104] = (__hip_bfloat16 (*)[104])(LB + 23296);
    __hip_bfloat16* VQ = (__hip_bfloat16*)(LB + 46592);
    float* OutF = (float*)(LB + 23296);

    const int wid = blockIdx.x, tid = threadIdx.x;
    const int lane = tid & 63, wv = tid >> 6;       // 8 waves
    const int l15 = lane & 15;
    const int g = lane >> 4;
    const int koff = g * 8;
    const int drow = g * 4;
    const bool oddg = (g >> 1) & 1;
    const int srcA = l15 + ((g & 1) << 5);
    const int srcB = srcA + 16;

    for (int t = tid; t < NTOK; t += 512) rowbase[t] = row_of(wid, t) * 96;
    for (int i = tid; i < 14 * 104; i += 512) {     // zero XS pad rows 98..111
        int r = 98 + i / 104, c = i % 104;
        XS[r][c] = __float2bfloat16(0.f);
    }

    // ---- LN1 -> XS bf16 (one wave per token)
    {
        float w0 = n1w[lane], b0 = n1b[lane];
        float w1_ = (lane < 32) ? n1w[64 + lane] : 0.f;
        float b1_ = (lane < 32) ? n1b[64 + lane] : 0.f;
        for (int t = wv; t < NTOK; t += 8) {
            int base = row_of(wid, t) * 96;
            float v0 = x[base + lane];
            float v1 = (lane < 32) ? x[base + 64 + lane] : 0.f;
            float s = v0 + v1;
            #pragma unroll
            for (int m = 32; m; m >>= 1) s += __shfl_xor(s, m, 64);
            float mean = s * (1.f / 96.f);
            float e0 = v0 - mean;
            float e1 = (lane < 32) ? (v1 - mean) : 0.f;
            float ss = e0 * e0 + e1 * e1;
            #pragma unroll
            for (int m = 32; m; m >>= 1) ss += __shfl_xor(ss, m, 64);
            float rstd = rsqrtf(ss * (1.f / 96.f) + 1e-5f);
            XS[t][lane] = __float2bfloat16(e0 * rstd * w0 + b0);
            if (lane < 32)
                XS[t][64 + lane] = __float2bfloat16(e1 * rstd * w1_ + b1_);
        }
    }
    __syncthreads();                                   // bar0: XS ready

    // ---- chunk q: Q = XS @ Wq^T, C-frags -> QB bounce
    __hip_bfloat16* QB = &VQ[0];                       // [112][104]
    for (int tile = wv; tile < 42; tile += 8) {
        int m0 = (tile / 6) * 16, nt = tile % 6, n0 = nt * 16;
        f32x4 acc = {0.f, 0.f, 0.f, 0.f};
        #pragma unroll
        for (int ks = 0; ks < 3; ++ks) {
            bf16x8 a = *(const bf16x8*)&XS[m0 + l15][ks * 32 + koff];
            bf16x8 b = usews ? loadB_sw(wsb, nt * 3 + ks, lane)
                             : loadB_f32(qkv_w, (n0 + l15) * 96 + ks * 32 + koff);
            acc = __builtin_amdgcn_mfma_f32_16x16x32_bf16(a, b, acc, 0, 0, 0);
        }
        float bb = qkv_b[n0 + l15];
        #pragma unroll
        for (int r = 0; r < 4; ++r) {
            float q = usews ? (acc[r] + bb * SCALE) : ((acc[r] + bb) * SCALE);
            QB[(m0 + drow + r) * 104 + n0 + l15] = __float2bfloat16(q);
        }
    }
    __syncthreads();                                   // bar1: QB ready

    // ---- Q preload to registers (tasks wv, wv+8, wv+16; some waves get 2)
    bf16x8 qf[3];
    #pragma unroll
    for (int i = 0; i < 3; ++i) {
        int task = wv + 8 * i;
        if (task < 21) {
            int s_ = task / 3, h_ = task - 3 * s_;
            qf[i] = *(const bf16x8*)&QB[(s_ * 16 + l15) * 104 + h_ * 32 + koff];
        }
    }
    __syncthreads();                                   // bar2: QB dead -> vT region

    // ---- vT tail zero + chunks k, v
    __hip_bfloat16* vT = &VQ[0];                       // [96][136]
    for (int i = tid; i < 96 * 38; i += 512) {
        int r = i / 38, c = 98 + (i - r * 38);
        vT[r * 136 + c] = __float2bfloat16(0.f);
    }
    for (int c = 1; c < 3; ++c) {
        for (int tile = wv; tile < 42; tile += 8) {
            int m0 = (tile / 6) * 16, nt = tile % 6, n0 = nt * 16;
            f32x4 acc = {0.f, 0.f, 0.f, 0.f};
            #pragma unroll
            for (int ks = 0; ks < 3; ++ks) {
                bf16x8 a = *(const bf16x8*)&XS[m0 + l15][ks * 32 + koff];
                bf16x8 b = usews ? loadB_sw(wsb, (c * 6 + nt) * 3 + ks, lane)
                                 : loadB_f32(qkv_w + c * 9216,
                                             (n0 + l15) * 96 + ks * 32 + koff);
                acc = __builtin_amdgcn_mfma_f32_16x16x32_bf16(a, b, acc, 0, 0, 0);
            }
            float bb = qkv_b[c * 96 + n0 + l15];
            if (c == 1) {
                #pragma unroll
                for (int r = 0; r < 4; ++r)
                    Kb[m0 + drow + r][n0 + l15] = __float2bfloat16(acc[r] + bb);
            } else {
                unsigned int d0 = pk2(acc[0] + bb, acc[1] + bb);
                unsigned int d1 = pk2(acc[2] + bb, acc[3] + bb);
                int u0 = m0 + drow;
                if (u0 < NTOK) {
                    unsigned int* p = (unsigned int*)&vT[(n0 + l15) * 136 + u0];
                    p[0] = d0;
                    if (u0 + 2 < NTOK) p[1] = d1;
                }
            }
        }
    }
    __syncthreads();                                   // bar3: Kb, vT ready

    // ---- head loop, barrier-free: (strip,head) tasks
    #pragma unroll 1
    for (int i = 0; i < 3; ++i) {
        int task = wv + 8 * i;
        if (task >= 21) break;
        int strip = task / 3, h = task - 3 * strip;

        f32x4 s[7];
        #pragma unroll
        for (int U = 0; U < 7; ++U) {
            bf16x8 ak = *(const bf16x8*)&Kb[U * 16 + l15][h * 32 + koff];
            f32x4 z = {0.f, 0.f, 0.f, 0.f};
            s[U] = __builtin_amdgcn_mfma_f32_16x16x32_bf16(ak, qf[i], z, 0, 0, 0);
        }
        if (usews) {
            const float* bmb = biasM + (((h * 7 + strip) * 7) << 8) + (lane << 2);
            #pragma unroll
            for (int U = 0; U < 7; ++U) {
                f32x4 bv = *(const f32x4*)(bmb + (U << 8));
                s[U][0] += bv[0]; s[U][1] += bv[1]; s[U][2] += bv[2]; s[U][3] += bv[3];
            }
        } else {
            int tq = strip * 16 + l15; if (tq > 97) tq = 97;
            int pt = pcode(tq);
            #pragma unroll
            for (int U = 0; U < 7; ++U)
                #pragma unroll
                for (int r = 0; r < 4; ++r) {
                    int u = U * 16 + drow + r; if (u > 97) u = 97;
                    s[U][r] += rpb[(pt - pcode(u) + 253) * 3 + h];
                }
        }
        if (drow > 0) { s[6][0] = -1e30f; s[6][1] = -1e30f; }
        s[6][2] = -1e30f; s[6][3] = -1e30f;
        f32x4 sumv = {0.f, 0.f, 0.f, 0.f};
        #pragma unroll
        for (int U = 0; U < 7; ++U) {
            #pragma unroll
            for (int r = 0; r < 4; ++r) { s[U][r] = __expf(s[U][r]); sumv[r] += s[U][r]; }
        }
        float hs = sumv[0] + sumv[1] + sumv[2] + sumv[3];
        hs += __shfl_xor(hs, 16, 64);
        hs += __shfl_xor(hs, 32, 64);
        float inv = 1.f / hs;
        unsigned int dwl[7], dwh[7];
        #pragma unroll
        for (int U = 0; U < 7; ++U) {
            dwl[U] = pk2(s[U][0] * inv, s[U][1] * inv);
            dwh[U] = pk2(s[U][2] * inv, s[U][3] * inv);
        }
        f32x4 acc0 = {0.f, 0.f, 0.f, 0.f}, acc1 = {0.f, 0.f, 0.f, 0.f};
        #pragma unroll
        for (int ks = 0; ks < 4; ++ks) {
            unsigned int D0, D1, D2, D3;
            if (ks < 3) {
                unsigned int e0 = __shfl((int)dwl[2 * ks], srcA, 64);
                unsigned int o0 = __shfl((int)dwl[2 * ks + 1], srcA, 64);
                unsigned int e1 = __shfl((int)dwh[2 * ks], srcA, 64);
                unsigned int o1 = __shfl((int)dwh[2 * ks + 1], srcA, 64);
                unsigned int e2 = __shfl((int)dwl[2 * ks], srcB, 64);
                unsigned int o2 = __shfl((int)dwl[2 * ks + 1], srcB, 64);
                unsigned int e3 = __shfl((int)dwh[2 * ks], srcB, 64);
                unsigned int o3 = __shfl((int)dwh[2 * ks + 1], srcB, 64);
                D0 = oddg ? o0 : e0; D1 = oddg ? o1 : e1;
                D2 = oddg ? o2 : e2; D3 = oddg ? o3 : e3;
            } else {
                unsigned int t0 = __shfl((int)dwl[6], srcA, 64);
                unsigned int t1 = __shfl((int)dwh[6], srcA, 64);
                unsigned int t2 = __shfl((int)dwl[6], srcB, 64);
                unsigned int t3 = __shfl((int)dwh[6], srcB, 64);
                D0 = (g < 2) ? t0 : 0u; D1 = (g < 2) ? t1 : 0u;
                D2 = (g < 2) ? t2 : 0u; D3 = (g < 2) ? t3 : 0u;
            }
            union { unsigned int d[4]; bf16x8 v; } af;
            af.d[0] = D0; af.d[1] = D1; af.d[2] = D2; af.d[3] = D3;
            bf16x8 b0 = *(const bf16x8*)&vT[(h * 32 + l15) * 136 + ks * 32 + koff];
            bf16x8 b1_ = *(const bf16x8*)&vT[(h * 32 + 16 + l15) * 136 + ks * 32 + koff];
            acc0 = __builtin_amdgcn_mfma_f32_16x16x32_bf16(af.v, b0, acc0, 0, 0, 0);
            acc1 = __builtin_amdgcn_mfma_f32_16x16x32_bf16(af.v, b1_, acc1, 0, 0, 0);
        }
        #pragma unroll
        for (int r = 0; r < 4; ++r) {
            XS[strip * 16 + drow + r][h * 32 + l15]      = __float2bfloat16(acc0[r]);
            XS[strip * 16 + drow + r][h * 32 + 16 + l15] = __float2bfloat16(acc1[r]);
        }
    }
    __syncthreads();                                   // bar4: attn-out ready; Kb/vT dead

    // ==== per-strip tail (waves 0..6): proj -> residual->OutF -> LN2 -> MLP ====
    if (wv < 7) {
        const int strip = wv, m0 = strip * 16;

        // proj GEMM + x residual -> OutF (fp32), LN2 stats on the fly
        f32x4 sAcc = {0.f, 0.f, 0.f, 0.f}, sqAcc = {0.f, 0.f, 0.f, 0.f};
        #pragma unroll
        for (int nt = 0; nt < 6; ++nt) {
            f32x4 acc = {0.f, 0.f, 0.f, 0.f};
            #pragma unroll
            for (int ks = 0; ks < 3; ++ks) {
                bf16x8 a = *(const bf16x8*)&XS[m0 + l15][ks * 32 + koff];
                bf16x8 b = usews ? loadB_sw(wsb, FR_PROJ + nt * 3 + ks, lane)
                                 : loadB_f32(proj_w, (nt * 16 + l15) * 96 + ks * 32 + koff);
                acc = __builtin_amdgcn_mfma_f32_16x16x32_bf16(a, b, acc, 0, 0, 0);
            }
            float pb = proj_b[nt * 16 + l15];
            #pragma unroll
            for (int r = 0; r < 4; ++r) {
                int t = m0 + drow + r;
                float rv = (t < NTOK) ? (acc[r] + pb + x[rowbase[t] + nt * 16 + l15]) : 0.f;
                OutF[t * 100 + nt * 16 + l15] = rv;
                sAcc[r] += rv; sqAcc[r] += rv * rv;
            }
        }
        // finish LN2 stats (reduce over the 16-lane l15 group)
        float mean[4], rstd[4];
        #pragma unroll
        for (int r = 0; r < 4; ++r) {
            float s = sAcc[r], sq = sqAcc[r];
            #pragma unroll
            for (int m = 1; m < 16; m <<= 1) {
                s  += __shfl_xor(s, m, 64);
                sq += __shfl_xor(sq, m, 64);
            }
            mean[r] = s * (1.f / 96.f);
            float var = sq * (1.f / 96.f) - mean[r] * mean[r];
            rstd[r] = rsqrtf(var + 1e-5f);
        }
        // normalized -> XS (wave-private rows)
        #pragma unroll
        for (int nt = 0; nt < 6; ++nt) {
            int cc = nt * 16 + l15;
            float w2_ = n2w[cc], b2_ = n2b[cc];
            #pragma unroll
            for (int r = 0; r < 4; ++r) {
                float rv = OutF[(m0 + drow + r) * 100 + cc];
                XS[m0 + drow + r][cc] =
                    __float2bfloat16((rv - mean[r]) * rstd[r] * w2_ + b2_);
            }
        }

        // MLP: per hc, two ht-pairs; pair p feeds shuffle phase ks2=p
        f32x4 yacc[6];
        #pragma unroll
        for (int nt = 0; nt < 6; ++nt) yacc[nt] = (f32x4){0.f, 0.f, 0.f, 0.f};

        #pragma unroll 1
        for (int hc = 0; hc < 6; ++hc) {
            #pragma unroll
            for (int p = 0; p < 2; ++p) {
                f32x4 s0 = {0.f, 0.f, 0.f, 0.f}, s1 = {0.f, 0.f, 0.f, 0.f};
                #pragma unroll
                for (int ks = 0; ks < 3; ++ks) {
                    bf16x8 xb = *(const bf16x8*)&XS[m0 + l15][ks * 32 + koff];
                    bf16x8 aw0 = usews ? loadB_sw(wsb, FR_FC1 + (hc * 4 + 2 * p) * 3 + ks, lane)
                                       : loadB_f32(w1, (hc * 64 + 2 * p * 16 + l15) * 96 + ks * 32 + koff);
                    bf16x8 aw1 = usews ? loadB_sw(wsb, FR_FC1 + (hc * 4 + 2 * p + 1) * 3 + ks, lane)
                                       : loadB_f32(w1, (hc * 64 + (2 * p + 1) * 16 + l15) * 96 + ks * 32 + koff);
                    s0 = __builtin_amdgcn_mfma_f32_16x16x32_bf16(aw0, xb, s0, 0, 0, 0);
                    s1 = __builtin_amdgcn_mfma_f32_16x16x32_bf16(aw1, xb, s1, 0, 0, 0);
                }
                f32x4 bv0 = *(const f32x4*)&b1[hc * 64 + 2 * p * 16 + drow];
                f32x4 bv1 = *(const f32x4*)&b1[hc * 64 + (2 * p + 1) * 16 + drow];
                unsigned int dl0 = pk2(gelu(s0[0] + bv0[0]), gelu(s0[1] + bv0[1]));
                unsigned int dh0 = pk2(gelu(s0[2] + bv0[2]), gelu(s0[3] + bv0[3]));
                unsigned int dl1 = pk2(gelu(s1[0] + bv1[0]), gelu(s1[1] + bv1[1]));
                unsigned int dh1 = pk2(gelu(s1[2] + bv1[2]), gelu(s1[3] + bv1[3]));

                unsigned int e0 = __shfl((int)dl0, srcA, 64);
                unsigned int o0 = __shfl((int)dl1, srcA, 64);
                unsigned int e1 = __shfl((int)dh0, srcA, 64);
                unsigned int o1 = __shfl((int)dh1, srcA, 64);
                unsigned int e2 = __shfl((int)dl0, srcB, 64);
                unsigned int o2 = __shfl((int)dl1, srcB, 64);
                unsigned int e3 = __shfl((int)dh0, srcB, 64);
                unsigned int o3 = __shfl((int)dh1, srcB, 64);
                union { unsigned int d[4]; bf16x8 v; } af;
                af.d[0] = oddg ? o0 : e0;
                af.d[1] = oddg ? o1 : e1;
                af.d[2] = oddg ? o2 : e2;
                af.d[3] = oddg ? o3 : e3;
                #pragma unroll
                for (int nt = 0; nt < 6; ++nt) {
                    bf16x8 bw = usews ? loadB_sw(wsb, FR_FC2 + (nt * 6 + hc) * 2 + p, lane)
                                      : loadB_f32(w2, (nt * 16 + l15) * 384 + hc * 64 + p * 32 + koff);
                    yacc[nt] = __builtin_amdgcn_mfma_f32_16x16x32_bf16(af.v, bw, yacc[nt], 0, 0, 0);
                }
            }
        }

        // final: OutF += yacc + fc2 bias (wave-private RMW)
        #pragma unroll
        for (int nt = 0; nt < 6; ++nt) {
            float bb2 = b2[nt * 16 + l15];
            #pragma unroll
            for (int r = 0; r < 4; ++r) {
                int t = m0 + drow + r;
                OutF[t * 100 + nt * 16 + l15] += yacc[nt][r] + bb2;
            }
        }
    }
    __syncthreads();                                   // bar5: OutF complete

    // ---- coalesced store (full 384B rows as f32x4)
    for (int j = tid; j < NTOK * 24; j += 512) {
        int row = j / 24, q = j - row * 24;
        *(f32x4*)&out[rowbase[row] + q * 4] = *(const f32x4*)&OutF[row * 100 + q * 4];
    }
}

extern "C" void kernel_launch(void* const* d_in, const int* in_sizes, int n_in,
                              void* d_out, int out_size, void* d_ws, size_t ws_size,
                              hipStream_t stream) {
    const float* x      = (const float*)d_in[0];
    const float* n1w    = (const float*)d_in[1];
    const float* n1b    = (const float*)d_in[2];
    const float* qkv_w  = (const float*)d_in[3];
    const float* qkv_b  = (const float*)d_in[4];
    const float* proj_w = (const float*)d_in[5];
    const float* proj_b = (const float*)d_in[6];
    const float* rpb    = (const float*)d_in[7];
    const float* n2w    = (const float*)d_in[8];
    const float* n2b    = (const float*)d_in[9];
    const float* fc1_w  = (const float*)d_in[10];
    const float* fc1_b  = (const float*)d_in[11];
    const float* fc2_w  = (const float*)d_in[12];
    const float* fc2_b  = (const float*)d_in[13];
    float* out = (float*)d_out;

    const int usews = (ws_size >= (size_t)WS_NEED) ? 1 : 0;
    __hip_bfloat16* wsb = (__hip_bfloat16*)d_ws;
    float* biasM = (float*)((char*)d_ws + WS_BIASM_BYTE);

    if (usews)
        prep_kernel<<<(WS_BF16_N + 37632 + 255) / 256, 256, 0, stream>>>(
            qkv_w, proj_w, fc1_w, fc2_w, rpb, wsb, biasM);

    fused_kernel<<<2048, 512, 0, stream>>>(x, n1w, n1b, qkv_w, qkv_b,
                                           proj_w, proj_b, rpb,
                                           n2w, n2b, fc1_w, fc1_b, fc2_w, fc2_b,
                                           wsb, biasM, usews, out);
}